// Round 1
// baseline (635.686 us; speedup 1.0000x reference)
//
#include <hip/hip_runtime.h>
#include <hip/hip_bf16.h>

// CrossAttUnit: fused per-segment cross-attention.
//   yk = Y @ k ; yq = Yhat @ q  (H=256 -> D=64, split-bf16 MFMA, 3 products)
//   M  = (1/8) yk @ yq^T  (64x64, split-bf16 MFMA)
//   attn = softmax_rows(M) + 1e-6 ; W = attn / colsum(attn)
// One block (256 thr, 4 waves) per segment; B = 4096 blocks.

#define H  256
#define D  64
#define L  64
#define LP 68   // padded LDS row stride in fp32 words (68*4=272B, 16B aligned, +4-bank skew)

typedef __attribute__((ext_vector_type(8))) short frag_b;   // 8 x bf16 (4 VGPR)
typedef __attribute__((ext_vector_type(4))) float frag_acc; // 4 x fp32

__device__ inline unsigned short f32_bf16_rne(float f) {
    unsigned u = __float_as_uint(f);
    u += 0x7FFFu + ((u >> 16) & 1u);   // round-to-nearest-even on sign-magnitude bits
    return (unsigned short)(u >> 16);
}
__device__ inline float bf16_f32(unsigned short h) {
    return __uint_as_float(((unsigned)h) << 16);
}

// Transpose + hi/lo split k,q into ws:
//  planes[0]      = kT_hi[64][256], planes[16384]  = kT_lo
//  planes[32768]  = qT_hi,          planes[49152]  = qT_lo
__global__ void prep_kq(const float* __restrict__ k, const float* __restrict__ q,
                        unsigned short* __restrict__ planes) {
    int tid = blockIdx.x * 256 + threadIdx.x;            // 0..32767
    const float* src = (tid < H * D) ? k : q;
    int base = (tid < H * D) ? 0 : 2 * H * D;
    int e = tid & (H * D - 1);
    int h = e >> 6, d = e & 63;                          // k[h][d]
    float x = src[e];
    unsigned short hi = f32_bf16_rne(x);
    float rem = x - bf16_f32(hi);
    unsigned short lo = f32_bf16_rne(rem);
    int o = d * H + h;                                   // transposed [d][h]
    planes[base + o] = hi;
    planes[base + H * D + o] = lo;
}

__global__ __launch_bounds__(256) void cross_attn(
        const float* __restrict__ yhat, const float* __restrict__ y,
        const unsigned short* __restrict__ planes, float* __restrict__ out) {
    __shared__ __align__(16) float s_yk[L * LP];
    __shared__ __align__(16) float s_yq[L * LP];
    __shared__ __align__(16) float s_M[L * LP];
    __shared__ float s_cs[4 * L];

    const int b    = blockIdx.x;
    const int tid  = threadIdx.x;
    const int wave = tid >> 6;
    const int lane = tid & 63;
    const int ln   = lane & 15;   // row-in-tile (A) / col-in-tile (B,C)
    const int kg   = lane >> 4;   // k-group quad

    // ================= Phase 1: projections =================
    // waves 0,1 -> yk rows 0-31 / 32-63 ; waves 2,3 -> yq rows 0-31 / 32-63
    const bool isQ = (wave >= 2);
    const float* src = isQ ? yhat : y;
    const frag_b* bph = (const frag_b*)(planes + (isQ ? 2 * H * D : 0)); // hi plane, short8 units
    const frag_b* bpl = bph + (H * D) / 8;                               // lo plane
    const int rowbase = (wave & 1) * 32;

    const frag_acc zf = {0.f, 0.f, 0.f, 0.f};
    frag_acc acc[2][4];
    #pragma unroll
    for (int rt = 0; rt < 2; rt++)
        #pragma unroll
        for (int t = 0; t < 4; t++) acc[rt][t] = zf;

    const float* abase = src + ((size_t)b * L + rowbase + ln) * H + kg * 8;

    #pragma unroll 2
    for (int ks = 0; ks < 8; ks++) {
        const int kb = ks * 32;
        frag_b ah[2], al[2];
        #pragma unroll
        for (int rt = 0; rt < 2; rt++) {
            const float4* ap = (const float4*)(abase + (size_t)rt * 16 * H + kb);
            float4 v0 = ap[0], v1 = ap[1];
            float xs[8] = {v0.x, v0.y, v0.z, v0.w, v1.x, v1.y, v1.z, v1.w};
            #pragma unroll
            for (int j = 0; j < 8; j++) {
                unsigned short hb = f32_bf16_rne(xs[j]);
                ah[rt][j] = (short)hb;
                al[rt][j] = (short)f32_bf16_rne(xs[j] - bf16_f32(hb));
            }
        }
        #pragma unroll
        for (int t = 0; t < 4; t++) {
            int n = t * 16 + ln;
            frag_b bh = bph[n * (H / 8) + ks * 4 + kg];
            frag_b bl = bpl[n * (H / 8) + ks * 4 + kg];
            #pragma unroll
            for (int rt = 0; rt < 2; rt++) {
                acc[rt][t] = __builtin_amdgcn_mfma_f32_16x16x32_bf16(ah[rt], bh, acc[rt][t], 0, 0, 0);
                acc[rt][t] = __builtin_amdgcn_mfma_f32_16x16x32_bf16(ah[rt], bl, acc[rt][t], 0, 0, 0);
                acc[rt][t] = __builtin_amdgcn_mfma_f32_16x16x32_bf16(al[rt], bh, acc[rt][t], 0, 0, 0);
            }
        }
    }
    // C/D layout: col = lane&15, row = (lane>>4)*4 + i  (verified m89/m91)
    {
        float* dstP = isQ ? s_yq : s_yk;
        #pragma unroll
        for (int rt = 0; rt < 2; rt++)
            #pragma unroll
            for (int t = 0; t < 4; t++)
                #pragma unroll
                for (int i = 0; i < 4; i++)
                    dstP[(rowbase + rt * 16 + kg * 4 + i) * LP + t * 16 + ln] = acc[rt][t][i];
    }
    __syncthreads();

    // ================= Phase 2: M = (1/8) * yk @ yq^T =================
    // wave w -> M rows w*16 .. w*16+15, all 64 cols
    frag_acc mac[4];
    #pragma unroll
    for (int t = 0; t < 4; t++) mac[t] = zf;

    #pragma unroll
    for (int dk = 0; dk < 2; dk++) {
        const int db = dk * 32;
        frag_b ah, al;
        {
            const float* ap = &s_yk[(wave * 16 + ln) * LP + db + kg * 8];
            #pragma unroll
            for (int j = 0; j < 8; j++) {
                float x = ap[j];
                unsigned short hb = f32_bf16_rne(x);
                ah[j] = (short)hb;
                al[j] = (short)f32_bf16_rne(x - bf16_f32(hb));
            }
        }
        #pragma unroll
        for (int t = 0; t < 4; t++) {
            frag_b bh, bl;
            const float* bp = &s_yq[(t * 16 + ln) * LP + db + kg * 8];
            #pragma unroll
            for (int j = 0; j < 8; j++) {
                float x = bp[j];
                unsigned short hb = f32_bf16_rne(x);
                bh[j] = (short)hb;
                bl[j] = (short)f32_bf16_rne(x - bf16_f32(hb));
            }
            mac[t] = __builtin_amdgcn_mfma_f32_16x16x32_bf16(ah, bh, mac[t], 0, 0, 0);
            mac[t] = __builtin_amdgcn_mfma_f32_16x16x32_bf16(ah, bl, mac[t], 0, 0, 0);
            mac[t] = __builtin_amdgcn_mfma_f32_16x16x32_bf16(al, bh, mac[t], 0, 0, 0);
        }
    }
    #pragma unroll
    for (int t = 0; t < 4; t++)
        #pragma unroll
        for (int i = 0; i < 4; i++)
            s_M[(wave * 16 + kg * 4 + i) * LP + t * 16 + ln] = 0.125f * mac[t][i];
    __syncthreads();

    // ================= Phase 3: softmax rows, column-normalize =================
    // wave w handles rows w*16 .. w*16+15; lane = column m
    float attn[16];
    float cs = 0.f;
    #pragma unroll
    for (int i = 0; i < 16; i++) {
        float v = s_M[(wave * 16 + i) * LP + lane];
        float mx = v;
        #pragma unroll
        for (int off = 32; off > 0; off >>= 1) mx = fmaxf(mx, __shfl_xor(mx, off, 64));
        float e = __expf(v - mx);
        float s = e;
        #pragma unroll
        for (int off = 32; off > 0; off >>= 1) s += __shfl_xor(s, off, 64);
        float a = e / s + 1e-6f;
        attn[i] = a;
        cs += a;
    }
    s_cs[wave * 64 + lane] = cs;
    __syncthreads();
    const float tot = s_cs[lane] + s_cs[64 + lane] + s_cs[128 + lane] + s_cs[192 + lane];
    const float inv = 1.f / tot;
    float* ob = out + (size_t)b * (L * L);
    #pragma unroll
    for (int i = 0; i < 16; i++)
        ob[(wave * 16 + i) * 64 + lane] = attn[i] * inv;
}

extern "C" void kernel_launch(void* const* d_in, const int* in_sizes, int n_in,
                              void* d_out, int out_size, void* d_ws, size_t ws_size,
                              hipStream_t stream) {
    const float* yhat = (const float*)d_in[0];
    const float* y    = (const float*)d_in[1];
    const float* k    = (const float*)d_in[2];
    const float* q    = (const float*)d_in[3];
    float* outp = (float*)d_out;
    unsigned short* planes = (unsigned short*)d_ws;   // 4 planes * 16384 ushort = 128 KB

    const int N = in_sizes[0] / H;    // 262144
    const int B = N / L;              // 4096

    prep_kq<<<(2 * H * D) / 256, 256, 0, stream>>>(k, q, planes);
    cross_attn<<<B, 256, 0, stream>>>(yhat, y, planes, outp);
}